// Round 9
// baseline (748.728 us; speedup 1.0000x reference)
//
#include <hip/hip_runtime.h>
#include <hip/hip_bf16.h>
#include <float.h>
#include <math.h>

#define BB 128
#define PP 1024
#define KNN 4
#define NROWS (BB * PP)

typedef __bf16 v8bf __attribute__((ext_vector_type(8)));
typedef float  v4f  __attribute__((ext_vector_type(4)));

__device__ inline unsigned short f2bs(float f) {
    __hip_bfloat16 h = __float2bfloat16(f);
    return *(unsigned short*)&h;
}
__device__ inline unsigned packbf2(float a, float b) {
    return (unsigned)f2bs(a) | ((unsigned)f2bs(b) << 16);
}
// bf16 pair (packed in u32) -> two f32, bit-exact
__device__ inline float bflo(unsigned u) { return __builtin_bit_cast(float, u << 16); }
__device__ inline float bfhi(unsigned u) { return __builtin_bit_cast(float, u & 0xFFFF0000u); }

// ---------------------------------------------------------------------------
// Pack kernel (unchanged)
// ---------------------------------------------------------------------------
__global__ __launch_bounds__(256)
void pack_kernel(const float* __restrict__ src, int D,
                 __hip_bfloat16* __restrict__ xh, __hip_bfloat16* __restrict__ xl,
                 float* __restrict__ sq)
{
    const int t = blockIdx.x * 256 + threadIdx.x;     // t < NROWS*4
    const int row = t >> 2, part = t & 3;
    float v[8];
    #pragma unroll
    for (int u = 0; u < 8; u++) {
        int d = part * 8 + u;
        v[u] = (d < D) ? src[(size_t)row * D + d] : 0.f;
    }
    float s = 0.f;
    unsigned int hw[4], lw[4];
    #pragma unroll
    for (int w = 0; w < 4; w++) {
        unsigned short h2[2], l2[2];
        #pragma unroll
        for (int e = 0; e < 2; e++) {
            float x = v[2 * w + e];
            __hip_bfloat16 hb = __float2bfloat16(x);
            float hf = __bfloat162float(hb);
            __hip_bfloat16 lb = __float2bfloat16(x - hf);
            h2[e] = *(unsigned short*)&hb;
            l2[e] = *(unsigned short*)&lb;
            s = fmaf(x, x, s);
        }
        hw[w] = (unsigned int)h2[0] | ((unsigned int)h2[1] << 16);
        lw[w] = (unsigned int)l2[0] | ((unsigned int)l2[1] << 16);
    }
    s += __shfl_xor(s, 1);
    s += __shfl_xor(s, 2);
    uint4 hv; hv.x = hw[0]; hv.y = hw[1]; hv.z = hw[2]; hv.w = hw[3];
    uint4 lv; lv.x = lw[0]; lv.y = lw[1]; lv.z = lw[2]; lv.w = lw[3];
    *(uint4*)&xh[(size_t)row * 32 + part * 8] = hv;
    *(uint4*)&xl[(size_t)row * 32 + part * 8] = lv;
    if (part == 0) sq[row] = s;
}

// ---------------------------------------------------------------------------
// MFMA kNN (unchanged from round 8 — passing)
// ---------------------------------------------------------------------------
__global__ __launch_bounds__(256, 4)
void knn_mfma(const __hip_bfloat16* __restrict__ xh, const __hip_bfloat16* __restrict__ xl,
              const float* __restrict__ sq, int* __restrict__ nidx)
{
    constexpr int PITCH = 129;
    __shared__ __align__(16) float sc[64 * PITCH];
    unsigned long long* cand64 = (unsigned long long*)sc;

    const int tid = threadIdx.x;
    const int wv = tid >> 6, lane = tid & 63;
    const int lr = lane & 15, lq = lane >> 4;
    const int b = blockIdx.y, i0 = blockIdx.x * 64;
    const size_t Rb = (size_t)b * PP;

    v8bf ah[4], al[4];
    #pragma unroll
    for (int it = 0; it < 4; it++) {
        size_t g = Rb + i0 + it * 16 + lr;
        ah[it] = __builtin_bit_cast(v8bf, *(const uint4*)(xh + g * 32 + lq * 8));
        al[it] = __builtin_bit_cast(v8bf, *(const uint4*)(xl + g * 32 + lq * 8));
    }

    const int r = tid & 63, qt = tid >> 6;
    unsigned long long k0 = ~0ull, k1 = ~0ull, k2 = ~0ull, k3 = ~0ull;

    for (int ch = 0; ch < 8; ch++) {
        #pragma unroll
        for (int jt2 = 0; jt2 < 2; jt2++) {
            const int tl = wv * 2 + jt2;
            const size_t gj = Rb + ch * 128 + tl * 16 + lr;
            v8bf bh = __builtin_bit_cast(v8bf, *(const uint4*)(xh + gj * 32 + lq * 8));
            v8bf bl = __builtin_bit_cast(v8bf, *(const uint4*)(xl + gj * 32 + lq * 8));
            const float sqv = sq[gj];
            #pragma unroll
            for (int it = 0; it < 4; it++) {
                v4f a = (v4f){0.f, 0.f, 0.f, 0.f};
                a = __builtin_amdgcn_mfma_f32_16x16x32_bf16(al[it], bl, a, 0, 0, 0);
                a = __builtin_amdgcn_mfma_f32_16x16x32_bf16(al[it], bh, a, 0, 0, 0);
                a = __builtin_amdgcn_mfma_f32_16x16x32_bf16(ah[it], bl, a, 0, 0, 0);
                a = __builtin_amdgcn_mfma_f32_16x16x32_bf16(ah[it], bh, a, 0, 0, 0);
                #pragma unroll
                for (int m = 0; m < 4; m++)
                    sc[(it * 16 + lq * 4 + m) * PITCH + tl * 16 + lr] =
                        fmaf(-2.f, a[m], sqv);
            }
        }
        __syncthreads();
        {
            const float* rowp = &sc[r * PITCH + qt * 32];
            const int jb = ch * 128 + qt * 32;
            #pragma unroll
            for (int u = 0; u < 32; u++) {
                float s = rowp[u];
                unsigned ub = __builtin_bit_cast(unsigned, s);
                unsigned mm = (unsigned)((int)ub >> 31);
                unsigned ord = ub ^ (mm | 0x80000000u);
                unsigned long long key =
                    ((unsigned long long)ord << 32) | (unsigned)(jb + u);
                unsigned long long t; bool c;
                c = key < k0; t = c ? key : k0; key = c ? k0 : key; k0 = t;
                c = key < k1; t = c ? key : k1; key = c ? k1 : key; k1 = t;
                c = key < k2; t = c ? key : k2; key = c ? k2 : key; k2 = t;
                c = key < k3; k3 = c ? key : k3;
            }
        }
        __syncthreads();
    }

    cand64[(qt * 4 + 0) * 64 + r] = k0;
    cand64[(qt * 4 + 1) * 64 + r] = k1;
    cand64[(qt * 4 + 2) * 64 + r] = k2;
    cand64[(qt * 4 + 3) * 64 + r] = k3;
    __syncthreads();

    if (tid < 64) {
        unsigned long long m0 = ~0ull, m1 = ~0ull, m2 = ~0ull, m3 = ~0ull;
        #pragma unroll
        for (int s2 = 0; s2 < 16; s2++) {
            unsigned long long key = cand64[s2 * 64 + tid];
            unsigned long long t; bool c;
            c = key < m0; t = c ? key : m0; key = c ? m0 : key; m0 = t;
            c = key < m1; t = c ? key : m1; key = c ? m1 : key; m1 = t;
            c = key < m2; t = c ? key : m2; key = c ? m2 : key; m2 = t;
            c = key < m3; m3 = c ? key : m3;
        }
        const int base = (int)Rb;
        int* op = nidx + (size_t)(Rb + i0 + tid) * KNN;
        op[0] = base + (int)((unsigned)m0 & 1023u);
        op[1] = base + (int)((unsigned)m1 & 1023u);
        op[2] = base + (int)((unsigned)m2 & 1023u);
        op[3] = base + (int)((unsigned)m3 & 1023u);
    }
}

// ---------------------------------------------------------------------------
// Edge-MLP v3 (MFMA): block = 64 points (256 edges), 4 waves, wave-private
// rows -> ZERO barriers. xe and h1 share one union buffer (pitch P).
// ---------------------------------------------------------------------------
template<int D, int H, int C, typename OT>
__global__ __launch_bounds__(256, 4)
void edge_mfma(const float* __restrict__ x, const int* __restrict__ nidx,
               const __hip_bfloat16* __restrict__ EW1, const __hip_bfloat16* __restrict__ EW2,
               const float* __restrict__ b1g, const float* __restrict__ b2g,
               OT* __restrict__ out)
{
    constexpr int NE = 256;
    constexpr int TDP = (D == 1) ? 32 : 64;   // padded K of GEMM1
    constexpr int DP  = TDP / 2;              // xj offset
    constexpr int P   = ((TDP > H) ? TDP : H) + 8;  // shared pitch (16B-aligned)
    constexpr int NT1 = H / 16, NT2 = C / 16;
    constexpr int KS1 = TDP / 32, KS2 = H / 32;

    __shared__ __hip_bfloat16 xe[NE * P];     // union: xe then h1

    const int tid = threadIdx.x;
    const int wv = tid >> 6, lane = tid & 63;
    const int lr = lane & 15, q = lane >> 4;
    const int p0 = blockIdx.x * 64;

    // ---- gather: wave handles its own 64 edges (rows wv*64 .. wv*64+64) ----
    {
        const int e = wv * 64 + lane;
        const int j = nidx[(size_t)p0 * KNN + e];
        const int pi = p0 + (e >> 2);
        if constexpr (D == 1) {
            #pragma unroll
            for (int s = 0; s < P / 8; s++) {
                uint4 z; z.x = 0u; z.y = 0u; z.z = 0u; z.w = 0u;
                *(uint4*)&xe[e * P + s * 8] = z;
            }
            xe[e * P + 0]  = __float2bfloat16(x[pi]);
            xe[e * P + DP] = __float2bfloat16(x[j]);
        } else {
            const float* si = x + (size_t)pi * D;
            const float* sj = x + (size_t)j * D;
            #pragma unroll
            for (int s = 0; s < D / 8; s++) {
                float4 f0 = *(const float4*)&si[s * 8];
                float4 f1 = *(const float4*)&si[s * 8 + 4];
                uint4 uv;
                uv.x = packbf2(f0.x, f0.y); uv.y = packbf2(f0.z, f0.w);
                uv.z = packbf2(f1.x, f1.y); uv.w = packbf2(f1.z, f1.w);
                *(uint4*)&xe[e * P + s * 8] = uv;
            }
            #pragma unroll
            for (int s = 0; s < D / 8; s++) {
                float4 f0 = *(const float4*)&sj[s * 8];
                float4 f1 = *(const float4*)&sj[s * 8 + 4];
                uint4 uv;
                uv.x = packbf2(f0.x, f0.y); uv.y = packbf2(f0.z, f0.w);
                uv.z = packbf2(f1.x, f1.y); uv.w = packbf2(f1.z, f1.w);
                *(uint4*)&xe[e * P + DP + s * 8] = uv;
            }
        }
    }
    // same-wave LDS ordering: no barrier needed (rows are wave-private)

    // ---- GEMM1: 4 m-tiles per wave, weights direct from global (L1-shared) ----
    v4f acc1[4][NT1];
    #pragma unroll
    for (int mi = 0; mi < 4; mi++)
        #pragma unroll
        for (int nt = 0; nt < NT1; nt++) acc1[mi][nt] = (v4f){0.f, 0.f, 0.f, 0.f};

    #pragma unroll
    for (int ks = 0; ks < KS1; ks++) {
        v8bf a[4];
        #pragma unroll
        for (int mi = 0; mi < 4; mi++)
            a[mi] = __builtin_bit_cast(v8bf,
                *(const uint4*)&xe[(wv * 64 + mi * 16 + lr) * P + ks * 32 + q * 8]);
        v8bf b[NT1];
        #pragma unroll
        for (int nt = 0; nt < NT1; nt++)
            b[nt] = __builtin_bit_cast(v8bf,
                *(const uint4*)(EW1 + (size_t)(nt * 16 + lr) * TDP + ks * 32 + q * 8));
        #pragma unroll
        for (int mi = 0; mi < 4; mi++)
            #pragma unroll
            for (int nt = 0; nt < NT1; nt++)
                acc1[mi][nt] = __builtin_amdgcn_mfma_f32_16x16x32_bf16(a[mi], b[nt], acc1[mi][nt], 0, 0, 0);
    }
    // epilogue: bias + relu -> h1 (same union, wave-private rows)
    #pragma unroll
    for (int nt = 0; nt < NT1; nt++) {
        const float bias = b1g[nt * 16 + lr];
        #pragma unroll
        for (int mi = 0; mi < 4; mi++) {
            #pragma unroll
            for (int m = 0; m < 4; m++) {
                int row = wv * 64 + mi * 16 + q * 4 + m;
                xe[row * P + nt * 16 + lr] =
                    __float2bfloat16(fmaxf(acc1[mi][nt][m] + bias, 0.f));
            }
        }
    }

    // ---- GEMM2 ----
    v4f acc2[4][NT2];
    #pragma unroll
    for (int mi = 0; mi < 4; mi++)
        #pragma unroll
        for (int nt = 0; nt < NT2; nt++) acc2[mi][nt] = (v4f){0.f, 0.f, 0.f, 0.f};

    #pragma unroll
    for (int ks = 0; ks < KS2; ks++) {
        v8bf a[4];
        #pragma unroll
        for (int mi = 0; mi < 4; mi++)
            a[mi] = __builtin_bit_cast(v8bf,
                *(const uint4*)&xe[(wv * 64 + mi * 16 + lr) * P + ks * 32 + q * 8]);
        v8bf b[NT2];
        #pragma unroll
        for (int nt = 0; nt < NT2; nt++)
            b[nt] = __builtin_bit_cast(v8bf,
                *(const uint4*)(EW2 + (size_t)(nt * 16 + lr) * H + ks * 32 + q * 8));
        #pragma unroll
        for (int mi = 0; mi < 4; mi++)
            #pragma unroll
            for (int nt = 0; nt < NT2; nt++)
                acc2[mi][nt] = __builtin_amdgcn_mfma_f32_16x16x32_bf16(a[mi], b[nt], acc2[mi][nt], 0, 0, 0);
    }
    // epilogue: max over 4 regs (= 4 edges of the point) + bias, store
    #pragma unroll
    for (int nt = 0; nt < NT2; nt++) {
        const int c = nt * 16 + lr;
        const float bias = b2g[c];
        #pragma unroll
        for (int mi = 0; mi < 4; mi++) {
            float v = fmaxf(fmaxf(acc2[mi][nt][0], acc2[mi][nt][1]),
                            fmaxf(acc2[mi][nt][2], acc2[mi][nt][3])) + bias;
            const int p = p0 + (wv * 4 + mi) * 4 + q;
            if constexpr (sizeof(OT) == 4) out[(size_t)p * C + c] = v;
            else                           out[(size_t)p * C + c] = __float2bfloat16(v);
        }
    }
}

// ---------------------------------------------------------------------------
// Weight prep (unchanged from round 8)
// ---------------------------------------------------------------------------
__global__ void prep_kernel(const float* __restrict__ mW1, const float* __restrict__ mW2,
                            const float* __restrict__ mW3,
                            const float* __restrict__ mb1, const float* __restrict__ mb2,
                            const float* __restrict__ mb3,
                            const float* __restrict__ c1W1, const float* __restrict__ c1W2,
                            const float* __restrict__ c2W1, const float* __restrict__ c2W2,
                            const float* __restrict__ c3W1, const float* __restrict__ c3W2,
                            __hip_bfloat16* __restrict__ WT1, __hip_bfloat16* __restrict__ WT2,
                            __hip_bfloat16* __restrict__ WT3, float* __restrict__ bp,
                            __hip_bfloat16* __restrict__ E11, __hip_bfloat16* __restrict__ E12,
                            __hip_bfloat16* __restrict__ E13,
                            __hip_bfloat16* __restrict__ E21, __hip_bfloat16* __restrict__ E22,
                            __hip_bfloat16* __restrict__ E23)
{
    const int t0 = blockIdx.x * blockDim.x + threadIdx.x;
    const int NT = gridDim.x * blockDim.x;
    for (int i = t0; i < 272 * 136; i += NT) {
        int n = i / 136, k = i - n * 136;
        WT1[i] = (n < 264 && k < 128) ? __float2bfloat16(mW1[(size_t)k * 264 + n]) : __float2bfloat16(0.f);
    }
    for (int i = t0; i < 272 * 296; i += NT) {
        int n = i / 296, k = i - n * 296;
        WT2[i] = (n < 264 && k < 264) ? __float2bfloat16(mW2[(size_t)k * 264 + n]) : __float2bfloat16(0.f);
        WT3[i] = (n < 264 && k < 264) ? __float2bfloat16(mW3[(size_t)k * 264 + n]) : __float2bfloat16(0.f);
    }
    for (int i = t0; i < 3 * 272; i += NT) {
        int l = i / 272, n = i - l * 272;
        const float* bsrc = (l == 0) ? mb1 : (l == 1) ? mb2 : mb3;
        bp[i] = (n < 264) ? bsrc[n] : 0.f;
    }
    for (int i = t0; i < 32 * 32; i += NT) {
        int h = i >> 5, k = i & 31;
        float v = (k == 0) ? (c1W1[h] - c1W1[32 + h]) : (k == 16 ? c1W1[32 + h] : 0.f);
        E11[i] = __float2bfloat16(v);
    }
    for (int i = t0; i < 32 * 64; i += NT) {
        int h = i >> 6, k = i & 63;
        float v = (k < 32) ? (c2W1[k * 32 + h] - c2W1[(k + 32) * 32 + h]) : c2W1[k * 32 + h];
        E12[i] = __float2bfloat16(v);
    }
    for (int i = t0; i < 64 * 64; i += NT) {
        int h = i >> 6, k = i & 63;
        float v = (k < 32) ? (c3W1[k * 64 + h] - c3W1[(k + 32) * 64 + h]) : c3W1[k * 64 + h];
        E13[i] = __float2bfloat16(v);
    }
    for (int i = t0; i < 32 * 32; i += NT) {
        int c = i >> 5, h = i & 31;
        E21[i] = __float2bfloat16(c1W2[h * 32 + c]);
        E22[i] = __float2bfloat16(c2W2[h * 32 + c]);
    }
    for (int i = t0; i < 64 * 64; i += NT) {
        int c = i >> 6, h = i & 63;
        E23[i] = __float2bfloat16(c3W2[h * 64 + c]);
    }
}

// ---------------------------------------------------------------------------
// Final MLP v4: wave-private rows. Wave w owns rows [16w,16w+16), iterates all
// 17 n-tiles -> weight loads identical across waves (L1-shared), and act
// reads/writes never cross waves -> ZERO barriers in the layer chain.
// One barrier before the cross-wave layer-4 tail.
// ---------------------------------------------------------------------------
__global__ __launch_bounds__(256, 3)
void mlp_kernel(const float* __restrict__ x1, const float* __restrict__ x2,
                const __hip_bfloat16* __restrict__ x3,
                const __hip_bfloat16* __restrict__ WT1, const __hip_bfloat16* __restrict__ WT2,
                const __hip_bfloat16* __restrict__ WT3, const float* __restrict__ bp,
                const float* __restrict__ mW4, const float* __restrict__ mb4,
                float* __restrict__ outp)
{
    constexpr int KPA = 296;
    __shared__ __hip_bfloat16 act[64 * KPA];           // 37.9 KB
    __shared__ __align__(16) float W4s[264 * 2 + 2];   // transposed: [c][k]
    __shared__ float lsm[64 * 2];

    const int tid = threadIdx.x;
    const int wv = tid >> 6, lane = tid & 63;
    const int rlane = lane & 15, ph = lane >> 4;
    const size_t row0 = (size_t)blockIdx.x * 64;

    // ---- wave-private staging: wave w stages rows [16w, 16w+16) ----
    {
        const int r = 16 * wv + (lane >> 2);     // local row
        const size_t g = row0 + r;
        const int cg = lane & 3;                 // col group: 4 x 32 cols
        if (cg < 2) {
            const float* src = (cg == 0 ? x1 : x2) + g * 32;
            #pragma unroll
            for (int s = 0; s < 4; s++) {
                float4 f0 = *(const float4*)&src[s * 8];
                float4 f1 = *(const float4*)&src[s * 8 + 4];
                uint4 uv;
                uv.x = packbf2(f0.x, f0.y); uv.y = packbf2(f0.z, f0.w);
                uv.z = packbf2(f1.x, f1.y); uv.w = packbf2(f1.z, f1.w);
                *(uint4*)&act[r * KPA + cg * 32 + s * 8] = uv;
            }
        } else {
            const __hip_bfloat16* src = x3 + g * 64 + (size_t)(cg - 2) * 32;
            #pragma unroll
            for (int s = 0; s < 4; s++)
                *(uint4*)&act[r * KPA + cg * 32 + s * 8] = *(const uint4*)&src[s * 8];
        }
        // zero cols 128..295 of this row (21 uint4, split over the 4 lanes)
        uint4 z; z.x = 0u; z.y = 0u; z.z = 0u; z.w = 0u;
        for (int s = cg; s < 21; s += 4)
            *(uint4*)&act[r * KPA + 128 + s * 8] = z;
    }
    // W4 tail staging (consumed only after the single barrier below)
    for (int t = tid; t < 530; t += 256) {
        if (t < 528) { int c = t / 264, k2 = t - c * 264; W4s[t] = mW4[(size_t)k2 * 2 + c]; }
        else W4s[t] = mb4[t - 528];
    }
    // NO barrier: each wave only touches its own act rows below.

    v4f acc[17];

    auto layer = [&](const __hip_bfloat16* __restrict__ WT, int KP, int NK,
                     const float* __restrict__ bias) {
        #pragma unroll
        for (int nt = 0; nt < 17; nt++) acc[nt] = (v4f){0.f, 0.f, 0.f, 0.f};

        for (int ks = 0; ks < NK; ks++) {
            uint4 u = *(const uint4*)&act[(16 * wv + rlane) * KPA + ks * 32 + ph * 8];
            v8bf bf = __builtin_bit_cast(v8bf, u);
            #pragma unroll
            for (int nt = 0; nt < 17; nt++) {
                uint4 ua = *(const uint4*)(WT + (size_t)(nt * 16 + rlane) * KP + ks * 32 + ph * 8);
                v8bf af = __builtin_bit_cast(v8bf, ua);
                acc[nt] = __builtin_amdgcn_mfma_f32_16x16x32_bf16(af, bf, acc[nt], 0, 0, 0);
            }
        }
        // epilogue: wave-private rows -> no barrier
        #pragma unroll
        for (int nt = 0; nt < 17; nt++) {
            const int col0 = nt * 16 + ph * 4;
            float4 bv = *(const float4*)&bias[col0];
            ushort4 pk;
            pk.x = f2bs(fmaxf(acc[nt][0] + bv.x, 0.f));
            pk.y = f2bs(fmaxf(acc[nt][1] + bv.y, 0.f));
            pk.z = f2bs(fmaxf(acc[nt][2] + bv.z, 0.f));
            pk.w = f2bs(fmaxf(acc[nt][3] + bv.w, 0.f));
            *(ushort4*)&act[(16 * wv + rlane) * KPA + col0] = pk;
        }
    };

    layer(WT1, 136, 4, bp);
    layer(WT2, 296, 9, bp + 272);
    layer(WT3, 296, 9, bp + 544);

    __syncthreads();   // tail mixes rows across waves

    // layer 4 (264 -> 2) + log_softmax, vectorized
    if (tid < 128) {
        int r = tid >> 1, c = tid & 1;
        const __hip_bfloat16* ap = &act[r * KPA];
        const float* wp = &W4s[c * 264];
        float s = 0.f;
        for (int k = 0; k < 264; k += 8) {
            uint4 u = *(const uint4*)&ap[k];
            float4 wa = *(const float4*)&wp[k];
            float4 wb = *(const float4*)&wp[k + 4];
            s = fmaf(bflo(u.x), wa.x, s); s = fmaf(bfhi(u.x), wa.y, s);
            s = fmaf(bflo(u.y), wa.z, s); s = fmaf(bfhi(u.y), wa.w, s);
            s = fmaf(bflo(u.z), wb.x, s); s = fmaf(bfhi(u.z), wb.y, s);
            s = fmaf(bflo(u.w), wb.z, s); s = fmaf(bfhi(u.w), wb.w, s);
        }
        lsm[tid] = s + W4s[528 + c];
    }
    __syncthreads();
    if (tid < 64) {
        float l0 = lsm[tid * 2 + 0], l1 = lsm[tid * 2 + 1];
        float m = fmaxf(l0, l1);
        float lse = m + logf(expf(l0 - m) + expf(l1 - m));
        float2 o; o.x = l0 - lse; o.y = l1 - lse;
        *(float2*)&outp[(row0 + tid) * 2] = o;
    }
}

// ---------------------------------------------------------------------------
extern "C" void kernel_launch(void* const* d_in, const int* in_sizes, int n_in,
                              void* d_out, int out_size, void* d_ws, size_t ws_size,
                              hipStream_t stream)
{
    const float* x    = (const float*)d_in[0];
    const float* c1W1 = (const float*)d_in[2];
    const float* c1b1 = (const float*)d_in[3];
    const float* c1W2 = (const float*)d_in[4];
    const float* c1b2 = (const float*)d_in[5];
    const float* c2W1 = (const float*)d_in[6];
    const float* c2b1 = (const float*)d_in[7];
    const float* c2W2 = (const float*)d_in[8];
    const float* c2b2 = (const float*)d_in[9];
    const float* c3W1 = (const float*)d_in[10];
    const float* c3b1 = (const float*)d_in[11];
    const float* c3W2 = (const float*)d_in[12];
    const float* c3b2 = (const float*)d_in[13];
    const float* mW1  = (const float*)d_in[14];
    const float* mb1  = (const float*)d_in[15];
    const float* mW2  = (const float*)d_in[16];
    const float* mb2  = (const float*)d_in[17];
    const float* mW3  = (const float*)d_in[18];
    const float* mb3  = (const float*)d_in[19];
    const float* mW4  = (const float*)d_in[20];
    const float* mb4  = (const float*)d_in[21];

    // workspace carve (~70 MB)
    float* x1 = (float*)d_ws;                                        // [N,32] f32
    float* x2 = x1 + (size_t)NROWS * 32;                             // [N,32] f32
    __hip_bfloat16* x3 = (__hip_bfloat16*)(x2 + (size_t)NROWS * 32); // [N,64] bf16
    int* nidx = (int*)(x3 + (size_t)NROWS * 64);                     // [N,4] i32
    __hip_bfloat16* WT1 = (__hip_bfloat16*)(nidx + (size_t)NROWS * 4);
    __hip_bfloat16* WT2 = WT1 + 272 * 136;
    __hip_bfloat16* WT3 = WT2 + 272 * 296;
    float* bp = (float*)(WT3 + 272 * 296);                           // [3][272] f32
    __hip_bfloat16* xph = (__hip_bfloat16*)(bp + 3 * 272);           // [N,32] bf16
    __hip_bfloat16* xpl = xph + (size_t)NROWS * 32;                  // [N,32] bf16
    float* sqw = (float*)(xpl + (size_t)NROWS * 32);                 // [N] f32
    __hip_bfloat16* E11 = (__hip_bfloat16*)(sqw + NROWS);            // [32][32]
    __hip_bfloat16* E12 = E11 + 32 * 32;                             // [32][64]
    __hip_bfloat16* E13 = E12 + 32 * 64;                             // [64][64]
    __hip_bfloat16* E21 = E13 + 64 * 64;                             // [32][32]
    __hip_bfloat16* E22 = E21 + 32 * 32;                             // [32][32]
    __hip_bfloat16* E23 = E22 + 32 * 32;                             // [64][64]

    prep_kernel<<<dim3(512), 256, 0, stream>>>(mW1, mW2, mW3, mb1, mb2, mb3,
                                               c1W1, c1W2, c2W1, c2W2, c3W1, c3W2,
                                               WT1, WT2, WT3, bp,
                                               E11, E12, E13, E21, E22, E23);

    dim3 kgrid(PP / 64, BB);
    dim3 pgrid(NROWS * 4 / 256);
    dim3 egrid(NROWS / 64);

    pack_kernel<<<pgrid, 256, 0, stream>>>(x, 1, xph, xpl, sqw);
    knn_mfma<<<kgrid, 256, 0, stream>>>(xph, xpl, sqw, nidx);
    edge_mfma<1, 32, 32, float><<<egrid, 256, 0, stream>>>(x, nidx, E11, E21, c1b1, c1b2, x1);

    pack_kernel<<<pgrid, 256, 0, stream>>>(x1, 32, xph, xpl, sqw);
    knn_mfma<<<kgrid, 256, 0, stream>>>(xph, xpl, sqw, nidx);
    edge_mfma<32, 32, 32, float><<<egrid, 256, 0, stream>>>(x1, nidx, E12, E22, c2b1, c2b2, x2);

    pack_kernel<<<pgrid, 256, 0, stream>>>(x2, 32, xph, xpl, sqw);
    knn_mfma<<<kgrid, 256, 0, stream>>>(xph, xpl, sqw, nidx);
    edge_mfma<32, 64, 64, __hip_bfloat16><<<egrid, 256, 0, stream>>>(x2, nidx, E13, E23, c3b1, c3b2, x3);

    mlp_kernel<<<dim3(NROWS / 64), 256, 0, stream>>>(x1, x2, x3, WT1, WT2, WT3, bp,
                                                     mW4, mb4, (float*)d_out);
}

// Round 10
// 585.680 us; speedup vs baseline: 1.2784x; 1.2784x over previous
//
#include <hip/hip_runtime.h>
#include <hip/hip_bf16.h>
#include <float.h>
#include <math.h>

#define BB 128
#define PP 1024
#define KNN 4
#define NROWS (BB * PP)

typedef __bf16 v8bf __attribute__((ext_vector_type(8)));
typedef float  v4f  __attribute__((ext_vector_type(4)));

__device__ inline unsigned short f2bs(float f) {
    __hip_bfloat16 h = __float2bfloat16(f);
    return *(unsigned short*)&h;
}
__device__ inline unsigned packbf2(float a, float b) {
    return (unsigned)f2bs(a) | ((unsigned)f2bs(b) << 16);
}
// bf16 pair (packed in u32) -> two f32, bit-exact
__device__ inline float bflo(unsigned u) { return __builtin_bit_cast(float, u << 16); }
__device__ inline float bfhi(unsigned u) { return __builtin_bit_cast(float, u & 0xFFFF0000u); }

// ---------------------------------------------------------------------------
// Pack kernel (unchanged)
// ---------------------------------------------------------------------------
__global__ __launch_bounds__(256)
void pack_kernel(const float* __restrict__ src, int D,
                 __hip_bfloat16* __restrict__ xh, __hip_bfloat16* __restrict__ xl,
                 float* __restrict__ sq)
{
    const int t = blockIdx.x * 256 + threadIdx.x;     // t < NROWS*4
    const int row = t >> 2, part = t & 3;
    float v[8];
    #pragma unroll
    for (int u = 0; u < 8; u++) {
        int d = part * 8 + u;
        v[u] = (d < D) ? src[(size_t)row * D + d] : 0.f;
    }
    float s = 0.f;
    unsigned int hw[4], lw[4];
    #pragma unroll
    for (int w = 0; w < 4; w++) {
        unsigned short h2[2], l2[2];
        #pragma unroll
        for (int e = 0; e < 2; e++) {
            float x = v[2 * w + e];
            __hip_bfloat16 hb = __float2bfloat16(x);
            float hf = __bfloat162float(hb);
            __hip_bfloat16 lb = __float2bfloat16(x - hf);
            h2[e] = *(unsigned short*)&hb;
            l2[e] = *(unsigned short*)&lb;
            s = fmaf(x, x, s);
        }
        hw[w] = (unsigned int)h2[0] | ((unsigned int)h2[1] << 16);
        lw[w] = (unsigned int)l2[0] | ((unsigned int)l2[1] << 16);
    }
    s += __shfl_xor(s, 1);
    s += __shfl_xor(s, 2);
    uint4 hv; hv.x = hw[0]; hv.y = hw[1]; hv.z = hw[2]; hv.w = hw[3];
    uint4 lv; lv.x = lw[0]; lv.y = lw[1]; lv.z = lw[2]; lv.w = lw[3];
    *(uint4*)&xh[(size_t)row * 32 + part * 8] = hv;
    *(uint4*)&xl[(size_t)row * 32 + part * 8] = lv;
    if (part == 0) sq[row] = s;
}

// ---------------------------------------------------------------------------
// MFMA kNN v4: distance math unchanged. Selection: branchless f32 push-down
// chain with index payload (1 cmp + 4 cndmask per slot vs 64-bit chain's 7).
// Within a thread j ascends -> strict < gives lex (score,idx) among ties.
// Cross-quarter merge uses full ord-u64 keys (order-independent).
// ---------------------------------------------------------------------------
__global__ __launch_bounds__(256, 4)
void knn_mfma(const __hip_bfloat16* __restrict__ xh, const __hip_bfloat16* __restrict__ xl,
              const float* __restrict__ sq, int* __restrict__ nidx)
{
    constexpr int PITCH = 129;
    __shared__ __align__(16) float sc[64 * PITCH];
    unsigned long long* cand64 = (unsigned long long*)sc;

    const int tid = threadIdx.x;
    const int wv = tid >> 6, lane = tid & 63;
    const int lr = lane & 15, lq = lane >> 4;
    const int b = blockIdx.y, i0 = blockIdx.x * 64;
    const size_t Rb = (size_t)b * PP;

    v8bf ah[4], al[4];
    #pragma unroll
    for (int it = 0; it < 4; it++) {
        size_t g = Rb + i0 + it * 16 + lr;
        ah[it] = __builtin_bit_cast(v8bf, *(const uint4*)(xh + g * 32 + lq * 8));
        al[it] = __builtin_bit_cast(v8bf, *(const uint4*)(xl + g * 32 + lq * 8));
    }

    const int r = tid & 63, qt = tid >> 6;
    float f0 = FLT_MAX, f1 = FLT_MAX, f2 = FLT_MAX, f3 = FLT_MAX;
    int   i0v = 0x7FFFFFFF, i1v = 0x7FFFFFFF, i2v = 0x7FFFFFFF, i3v = 0x7FFFFFFF;

    for (int ch = 0; ch < 8; ch++) {
        #pragma unroll
        for (int jt2 = 0; jt2 < 2; jt2++) {
            const int tl = wv * 2 + jt2;
            const size_t gj = Rb + ch * 128 + tl * 16 + lr;
            v8bf bh = __builtin_bit_cast(v8bf, *(const uint4*)(xh + gj * 32 + lq * 8));
            v8bf bl = __builtin_bit_cast(v8bf, *(const uint4*)(xl + gj * 32 + lq * 8));
            const float sqv = sq[gj];
            #pragma unroll
            for (int it = 0; it < 4; it++) {
                v4f a = (v4f){0.f, 0.f, 0.f, 0.f};
                a = __builtin_amdgcn_mfma_f32_16x16x32_bf16(al[it], bl, a, 0, 0, 0);
                a = __builtin_amdgcn_mfma_f32_16x16x32_bf16(al[it], bh, a, 0, 0, 0);
                a = __builtin_amdgcn_mfma_f32_16x16x32_bf16(ah[it], bl, a, 0, 0, 0);
                a = __builtin_amdgcn_mfma_f32_16x16x32_bf16(ah[it], bh, a, 0, 0, 0);
                #pragma unroll
                for (int m = 0; m < 4; m++)
                    sc[(it * 16 + lq * 4 + m) * PITCH + tl * 16 + lr] =
                        fmaf(-2.f, a[m], sqv);
            }
        }
        __syncthreads();
        {
            const float* rowp = &sc[r * PITCH + qt * 32];
            const int jb = ch * 128 + qt * 32;
            #pragma unroll
            for (int u = 0; u < 32; u++) {
                float s = rowp[u];
                int j = jb + u;
                bool c; float tf; int tj;
                c = s < f0; tf = c ? s : f0; tj = c ? j : i0v;
                float s1 = c ? f0 : s; int j1 = c ? i0v : j;
                f0 = tf; i0v = tj;
                c = s1 < f1; tf = c ? s1 : f1; tj = c ? j1 : i1v;
                float s2 = c ? f1 : s1; int j2 = c ? i1v : j1;
                f1 = tf; i1v = tj;
                c = s2 < f2; tf = c ? s2 : f2; tj = c ? j2 : i2v;
                float s3 = c ? f2 : s2; int j3 = c ? i2v : j2;
                f2 = tf; i2v = tj;
                c = s3 < f3; f3 = c ? s3 : f3; i3v = c ? j3 : i3v;
            }
        }
        __syncthreads();
    }

    // dump per-quarter candidates as ord-u64 keys (alias over sc)
    auto mk = [](float f, int j) {
        unsigned ub = __builtin_bit_cast(unsigned, f);
        unsigned mm = (unsigned)((int)ub >> 31);
        unsigned ord = ub ^ (mm | 0x80000000u);
        return ((unsigned long long)ord << 32) | (unsigned)j;
    };
    cand64[(qt * 4 + 0) * 64 + r] = mk(f0, i0v);
    cand64[(qt * 4 + 1) * 64 + r] = mk(f1, i1v);
    cand64[(qt * 4 + 2) * 64 + r] = mk(f2, i2v);
    cand64[(qt * 4 + 3) * 64 + r] = mk(f3, i3v);
    __syncthreads();

    if (tid < 64) {
        unsigned long long m0 = ~0ull, m1 = ~0ull, m2 = ~0ull, m3 = ~0ull;
        #pragma unroll
        for (int s2 = 0; s2 < 16; s2++) {
            unsigned long long key = cand64[s2 * 64 + tid];
            unsigned long long t; bool c;
            c = key < m0; t = c ? key : m0; key = c ? m0 : key; m0 = t;
            c = key < m1; t = c ? key : m1; key = c ? m1 : key; m1 = t;
            c = key < m2; t = c ? key : m2; key = c ? m2 : key; m2 = t;
            c = key < m3; m3 = c ? key : m3;
        }
        const int base = (int)Rb;
        int* op = nidx + (size_t)(Rb + i0 + tid) * KNN;
        op[0] = base + (int)((unsigned)m0 & 1023u);
        op[1] = base + (int)((unsigned)m1 & 1023u);
        op[2] = base + (int)((unsigned)m2 & 1023u);
        op[3] = base + (int)((unsigned)m3 & 1023u);
    }
}

// ---------------------------------------------------------------------------
// Edge-MLP v3 (MFMA, 64 pts/block, barrier-free) — unchanged from round 9
// ---------------------------------------------------------------------------
template<int D, int H, int C, typename OT>
__global__ __launch_bounds__(256, 4)
void edge_mfma(const float* __restrict__ x, const int* __restrict__ nidx,
               const __hip_bfloat16* __restrict__ EW1, const __hip_bfloat16* __restrict__ EW2,
               const float* __restrict__ b1g, const float* __restrict__ b2g,
               OT* __restrict__ out)
{
    constexpr int NE = 256;
    constexpr int TDP = (D == 1) ? 32 : 64;
    constexpr int DP  = TDP / 2;
    constexpr int P   = ((TDP > H) ? TDP : H) + 8;
    constexpr int NT1 = H / 16, NT2 = C / 16;
    constexpr int KS1 = TDP / 32, KS2 = H / 32;

    __shared__ __hip_bfloat16 xe[NE * P];

    const int tid = threadIdx.x;
    const int wv = tid >> 6, lane = tid & 63;
    const int lr = lane & 15, q = lane >> 4;
    const int p0 = blockIdx.x * 64;

    {
        const int e = wv * 64 + lane;
        const int j = nidx[(size_t)p0 * KNN + e];
        const int pi = p0 + (e >> 2);
        if constexpr (D == 1) {
            #pragma unroll
            for (int s = 0; s < P / 8; s++) {
                uint4 z; z.x = 0u; z.y = 0u; z.z = 0u; z.w = 0u;
                *(uint4*)&xe[e * P + s * 8] = z;
            }
            xe[e * P + 0]  = __float2bfloat16(x[pi]);
            xe[e * P + DP] = __float2bfloat16(x[j]);
        } else {
            const float* si = x + (size_t)pi * D;
            const float* sj = x + (size_t)j * D;
            #pragma unroll
            for (int s = 0; s < D / 8; s++) {
                float4 f0 = *(const float4*)&si[s * 8];
                float4 f1 = *(const float4*)&si[s * 8 + 4];
                uint4 uv;
                uv.x = packbf2(f0.x, f0.y); uv.y = packbf2(f0.z, f0.w);
                uv.z = packbf2(f1.x, f1.y); uv.w = packbf2(f1.z, f1.w);
                *(uint4*)&xe[e * P + s * 8] = uv;
            }
            #pragma unroll
            for (int s = 0; s < D / 8; s++) {
                float4 f0 = *(const float4*)&sj[s * 8];
                float4 f1 = *(const float4*)&sj[s * 8 + 4];
                uint4 uv;
                uv.x = packbf2(f0.x, f0.y); uv.y = packbf2(f0.z, f0.w);
                uv.z = packbf2(f1.x, f1.y); uv.w = packbf2(f1.z, f1.w);
                *(uint4*)&xe[e * P + DP + s * 8] = uv;
            }
        }
    }

    v4f acc1[4][NT1];
    #pragma unroll
    for (int mi = 0; mi < 4; mi++)
        #pragma unroll
        for (int nt = 0; nt < NT1; nt++) acc1[mi][nt] = (v4f){0.f, 0.f, 0.f, 0.f};

    #pragma unroll
    for (int ks = 0; ks < KS1; ks++) {
        v8bf a[4];
        #pragma unroll
        for (int mi = 0; mi < 4; mi++)
            a[mi] = __builtin_bit_cast(v8bf,
                *(const uint4*)&xe[(wv * 64 + mi * 16 + lr) * P + ks * 32 + q * 8]);
        v8bf b[NT1];
        #pragma unroll
        for (int nt = 0; nt < NT1; nt++)
            b[nt] = __builtin_bit_cast(v8bf,
                *(const uint4*)(EW1 + (size_t)(nt * 16 + lr) * TDP + ks * 32 + q * 8));
        #pragma unroll
        for (int mi = 0; mi < 4; mi++)
            #pragma unroll
            for (int nt = 0; nt < NT1; nt++)
                acc1[mi][nt] = __builtin_amdgcn_mfma_f32_16x16x32_bf16(a[mi], b[nt], acc1[mi][nt], 0, 0, 0);
    }
    #pragma unroll
    for (int nt = 0; nt < NT1; nt++) {
        const float bias = b1g[nt * 16 + lr];
        #pragma unroll
        for (int mi = 0; mi < 4; mi++) {
            #pragma unroll
            for (int m = 0; m < 4; m++) {
                int row = wv * 64 + mi * 16 + q * 4 + m;
                xe[row * P + nt * 16 + lr] =
                    __float2bfloat16(fmaxf(acc1[mi][nt][m] + bias, 0.f));
            }
        }
    }

    v4f acc2[4][NT2];
    #pragma unroll
    for (int mi = 0; mi < 4; mi++)
        #pragma unroll
        for (int nt = 0; nt < NT2; nt++) acc2[mi][nt] = (v4f){0.f, 0.f, 0.f, 0.f};

    #pragma unroll
    for (int ks = 0; ks < KS2; ks++) {
        v8bf a[4];
        #pragma unroll
        for (int mi = 0; mi < 4; mi++)
            a[mi] = __builtin_bit_cast(v8bf,
                *(const uint4*)&xe[(wv * 64 + mi * 16 + lr) * P + ks * 32 + q * 8]);
        v8bf b[NT2];
        #pragma unroll
        for (int nt = 0; nt < NT2; nt++)
            b[nt] = __builtin_bit_cast(v8bf,
                *(const uint4*)(EW2 + (size_t)(nt * 16 + lr) * H + ks * 32 + q * 8));
        #pragma unroll
        for (int mi = 0; mi < 4; mi++)
            #pragma unroll
            for (int nt = 0; nt < NT2; nt++)
                acc2[mi][nt] = __builtin_amdgcn_mfma_f32_16x16x32_bf16(a[mi], b[nt], acc2[mi][nt], 0, 0, 0);
    }
    #pragma unroll
    for (int nt = 0; nt < NT2; nt++) {
        const int c = nt * 16 + lr;
        const float bias = b2g[c];
        #pragma unroll
        for (int mi = 0; mi < 4; mi++) {
            float v = fmaxf(fmaxf(acc2[mi][nt][0], acc2[mi][nt][1]),
                            fmaxf(acc2[mi][nt][2], acc2[mi][nt][3])) + bias;
            const int p = p0 + (wv * 4 + mi) * 4 + q;
            if constexpr (sizeof(OT) == 4) out[(size_t)p * C + c] = v;
            else                           out[(size_t)p * C + c] = __float2bfloat16(v);
        }
    }
}

// ---------------------------------------------------------------------------
// Weight prep (unchanged)
// ---------------------------------------------------------------------------
__global__ void prep_kernel(const float* __restrict__ mW1, const float* __restrict__ mW2,
                            const float* __restrict__ mW3,
                            const float* __restrict__ mb1, const float* __restrict__ mb2,
                            const float* __restrict__ mb3,
                            const float* __restrict__ c1W1, const float* __restrict__ c1W2,
                            const float* __restrict__ c2W1, const float* __restrict__ c2W2,
                            const float* __restrict__ c3W1, const float* __restrict__ c3W2,
                            __hip_bfloat16* __restrict__ WT1, __hip_bfloat16* __restrict__ WT2,
                            __hip_bfloat16* __restrict__ WT3, float* __restrict__ bp,
                            __hip_bfloat16* __restrict__ E11, __hip_bfloat16* __restrict__ E12,
                            __hip_bfloat16* __restrict__ E13,
                            __hip_bfloat16* __restrict__ E21, __hip_bfloat16* __restrict__ E22,
                            __hip_bfloat16* __restrict__ E23)
{
    const int t0 = blockIdx.x * blockDim.x + threadIdx.x;
    const int NT = gridDim.x * blockDim.x;
    for (int i = t0; i < 272 * 136; i += NT) {
        int n = i / 136, k = i - n * 136;
        WT1[i] = (n < 264 && k < 128) ? __float2bfloat16(mW1[(size_t)k * 264 + n]) : __float2bfloat16(0.f);
    }
    for (int i = t0; i < 272 * 296; i += NT) {
        int n = i / 296, k = i - n * 296;
        WT2[i] = (n < 264 && k < 264) ? __float2bfloat16(mW2[(size_t)k * 264 + n]) : __float2bfloat16(0.f);
        WT3[i] = (n < 264 && k < 264) ? __float2bfloat16(mW3[(size_t)k * 264 + n]) : __float2bfloat16(0.f);
    }
    for (int i = t0; i < 3 * 272; i += NT) {
        int l = i / 272, n = i - l * 272;
        const float* bsrc = (l == 0) ? mb1 : (l == 1) ? mb2 : mb3;
        bp[i] = (n < 264) ? bsrc[n] : 0.f;
    }
    for (int i = t0; i < 32 * 32; i += NT) {
        int h = i >> 5, k = i & 31;
        float v = (k == 0) ? (c1W1[h] - c1W1[32 + h]) : (k == 16 ? c1W1[32 + h] : 0.f);
        E11[i] = __float2bfloat16(v);
    }
    for (int i = t0; i < 32 * 64; i += NT) {
        int h = i >> 6, k = i & 63;
        float v = (k < 32) ? (c2W1[k * 32 + h] - c2W1[(k + 32) * 32 + h]) : c2W1[k * 32 + h];
        E12[i] = __float2bfloat16(v);
    }
    for (int i = t0; i < 64 * 64; i += NT) {
        int h = i >> 6, k = i & 63;
        float v = (k < 32) ? (c3W1[k * 64 + h] - c3W1[(k + 32) * 64 + h]) : c3W1[k * 64 + h];
        E13[i] = __float2bfloat16(v);
    }
    for (int i = t0; i < 32 * 32; i += NT) {
        int c = i >> 5, h = i & 31;
        E21[i] = __float2bfloat16(c1W2[h * 32 + c]);
        E22[i] = __float2bfloat16(c2W2[h * 32 + c]);
    }
    for (int i = t0; i < 64 * 64; i += NT) {
        int c = i >> 6, h = i & 63;
        E23[i] = __float2bfloat16(c3W2[h * 64 + c]);
    }
}

// ---------------------------------------------------------------------------
// Final MLP — REVERT to round-8 structure (measured 150 µs): 4 waves split
// 17 n-tiles (4-5 each), 4 row-tiles per wave -> 20 MFMA per 5 weight loads.
// ---------------------------------------------------------------------------
__global__ __launch_bounds__(256, 3)
void mlp_kernel(const float* __restrict__ x1, const float* __restrict__ x2,
                const __hip_bfloat16* __restrict__ x3,
                const __hip_bfloat16* __restrict__ WT1, const __hip_bfloat16* __restrict__ WT2,
                const __hip_bfloat16* __restrict__ WT3, const float* __restrict__ bp,
                const float* __restrict__ mW4, const float* __restrict__ mb4,
                float* __restrict__ outp)
{
    constexpr int KPA = 296;
    __shared__ __hip_bfloat16 act[64 * KPA];
    __shared__ __align__(16) float W4s[264 * 2 + 2];
    __shared__ float lsm[64 * 2];

    const int tid = threadIdx.x;
    const int wv = tid >> 6, lane = tid & 63;
    const int rlane = lane & 15, ph = lane >> 4;
    const size_t row0 = (size_t)blockIdx.x * 64;

    for (int t = tid; t < 64 * KPA / 2; t += 256) ((unsigned int*)act)[t] = 0u;
    __syncthreads();
    for (int t = tid; t < 64 * 128; t += 256) {
        int r = t >> 7, c = t & 127;
        size_t g = row0 + r;
        __hip_bfloat16 v;
        if (c < 32)       v = __float2bfloat16(x1[g * 32 + c]);
        else if (c < 64)  v = __float2bfloat16(x2[g * 32 + (c - 32)]);
        else              v = x3[g * 64 + (c - 64)];
        act[r * KPA + c] = v;
    }
    for (int t = tid; t < 530; t += 256) {
        if (t < 528) { int c = t / 264, k2 = t - c * 264; W4s[t] = mW4[(size_t)k2 * 2 + c]; }
        else W4s[t] = mb4[t - 528];
    }
    __syncthreads();

    const int ntc = (wv == 0) ? 5 : 4;
    v4f acc[5][4];

    auto layer = [&](const __hip_bfloat16* __restrict__ WT, int KP, int NK,
                     const float* __restrict__ bias) {
        #pragma unroll
        for (int i = 0; i < 5; i++)
            #pragma unroll
            for (int rt = 0; rt < 4; rt++) acc[i][rt] = (v4f){0.f, 0.f, 0.f, 0.f};

        for (int ks = 0; ks < NK; ks++) {
            v8bf bf[4];
            #pragma unroll
            for (int rt = 0; rt < 4; rt++) {
                uint4 u = *(const uint4*)&act[(rt * 16 + rlane) * KPA + ks * 32 + ph * 8];
                bf[rt] = __builtin_bit_cast(v8bf, u);
            }
            #pragma unroll
            for (int i = 0; i < 5; i++) {
                if (i < ntc) {
                    int nt = wv + 4 * i;
                    uint4 ua = *(const uint4*)(WT + (size_t)(nt * 16 + rlane) * KP + ks * 32 + ph * 8);
                    v8bf af = __builtin_bit_cast(v8bf, ua);
                    #pragma unroll
                    for (int rt = 0; rt < 4; rt++)
                        acc[i][rt] = __builtin_amdgcn_mfma_f32_16x16x32_bf16(af, bf[rt], acc[i][rt], 0, 0, 0);
                }
            }
        }
        __syncthreads();
        #pragma unroll
        for (int i = 0; i < 5; i++) {
            if (i < ntc) {
                int nt = wv + 4 * i;
                int col0 = nt * 16 + ph * 4;
                float4 bv = *(const float4*)&bias[col0];
                #pragma unroll
                for (int rt = 0; rt < 4; rt++) {
                    int row = rt * 16 + rlane;
                    ushort4 pk;
                    pk.x = f2bs(fmaxf(acc[i][rt][0] + bv.x, 0.f));
                    pk.y = f2bs(fmaxf(acc[i][rt][1] + bv.y, 0.f));
                    pk.z = f2bs(fmaxf(acc[i][rt][2] + bv.z, 0.f));
                    pk.w = f2bs(fmaxf(acc[i][rt][3] + bv.w, 0.f));
                    *(ushort4*)&act[row * KPA + col0] = pk;
                }
            }
        }
        __syncthreads();
    };

    layer(WT1, 136, 4, bp);
    layer(WT2, 296, 9, bp + 272);
    layer(WT3, 296, 9, bp + 544);

    if (tid < 128) {
        int r = tid >> 1, c = tid & 1;
        const __hip_bfloat16* ap = &act[r * KPA];
        const float* wp = &W4s[c * 264];
        float s = 0.f;
        for (int k = 0; k < 264; k += 8) {
            uint4 u = *(const uint4*)&ap[k];
            float4 wa = *(const float4*)&wp[k];
            float4 wb = *(const float4*)&wp[k + 4];
            s = fmaf(bflo(u.x), wa.x, s); s = fmaf(bfhi(u.x), wa.y, s);
            s = fmaf(bflo(u.y), wa.z, s); s = fmaf(bfhi(u.y), wa.w, s);
            s = fmaf(bflo(u.z), wb.x, s); s = fmaf(bfhi(u.z), wb.y, s);
            s = fmaf(bflo(u.w), wb.z, s); s = fmaf(bfhi(u.w), wb.w, s);
        }
        lsm[tid] = s + W4s[528 + c];
    }
    __syncthreads();
    if (tid < 64) {
        float l0 = lsm[tid * 2 + 0], l1 = lsm[tid * 2 + 1];
        float m = fmaxf(l0, l1);
        float lse = m + logf(expf(l0 - m) + expf(l1 - m));
        float2 o; o.x = l0 - lse; o.y = l1 - lse;
        *(float2*)&outp[(row0 + tid) * 2] = o;
    }
}

// ---------------------------------------------------------------------------
extern "C" void kernel_launch(void* const* d_in, const int* in_sizes, int n_in,
                              void* d_out, int out_size, void* d_ws, size_t ws_size,
                              hipStream_t stream)
{
    const float* x    = (const float*)d_in[0];
    const float* c1W1 = (const float*)d_in[2];
    const float* c1b1 = (const float*)d_in[3];
    const float* c1W2 = (const float*)d_in[4];
    const float* c1b2 = (const float*)d_in[5];
    const float* c2W1 = (const float*)d_in[6];
    const float* c2b1 = (const float*)d_in[7];
    const float* c2W2 = (const float*)d_in[8];
    const float* c2b2 = (const float*)d_in[9];
    const float* c3W1 = (const float*)d_in[10];
    const float* c3b1 = (const float*)d_in[11];
    const float* c3W2 = (const float*)d_in[12];
    const float* c3b2 = (const float*)d_in[13];
    const float* mW1  = (const float*)d_in[14];
    const float* mb1  = (const float*)d_in[15];
    const float* mW2  = (const float*)d_in[16];
    const float* mb2  = (const float*)d_in[17];
    const float* mW3  = (const float*)d_in[18];
    const float* mb3  = (const float*)d_in[19];
    const float* mW4  = (const float*)d_in[20];
    const float* mb4  = (const float*)d_in[21];

    // workspace carve (~70 MB)
    float* x1 = (float*)d_ws;                                        // [N,32] f32
    float* x2 = x1 + (size_t)NROWS * 32;                             // [N,32] f32
    __hip_bfloat16* x3 = (__hip_bfloat16*)(x2 + (size_t)NROWS * 32); // [N,64] bf16
    int* nidx = (int*)(x3 + (size_t)NROWS * 64);                     // [N,4] i32
    __hip_bfloat16* WT1 = (__hip_bfloat16*)(nidx + (size_t)NROWS * 4);
    __hip_bfloat16* WT2 = WT1 + 272 * 136;
    __hip_bfloat16* WT3 = WT2 + 272 * 296;
    float* bp = (float*)(WT3 + 272 * 296);                           // [3][272] f32
    __hip_bfloat16* xph = (__hip_bfloat16*)(bp + 3 * 272);           // [N,32] bf16
    __hip_bfloat16* xpl = xph + (size_t)NROWS * 32;                  // [N,32] bf16
    float* sqw = (float*)(xpl + (size_t)NROWS * 32);                 // [N] f32
    __hip_bfloat16* E11 = (__hip_bfloat16*)(sqw + NROWS);            // [32][32]
    __hip_bfloat16* E12 = E11 + 32 * 32;                             // [32][64]
    __hip_bfloat16* E13 = E12 + 32 * 64;                             // [64][64]
    __hip_bfloat16* E21 = E13 + 64 * 64;                             // [32][32]
    __hip_bfloat16* E22 = E21 + 32 * 32;                             // [32][32]
    __hip_bfloat16* E23 = E22 + 32 * 32;                             // [64][64]

    prep_kernel<<<dim3(512), 256, 0, stream>>>(mW1, mW2, mW3, mb1, mb2, mb3,
                                               c1W1, c1W2, c2W1, c2W2, c3W1, c3W2,
                                               WT1, WT2, WT3, bp,
                                               E11, E12, E13, E21, E22, E23);

    dim3 kgrid(PP / 64, BB);
    dim3 pgrid(NROWS * 4 / 256);
    dim3 egrid(NROWS / 64);

    pack_kernel<<<pgrid, 256, 0, stream>>>(x, 1, xph, xpl, sqw);
    knn_mfma<<<kgrid, 256, 0, stream>>>(xph, xpl, sqw, nidx);
    edge_mfma<1, 32, 32, float><<<egrid, 256, 0, stream>>>(x, nidx, E11, E21, c1b1, c1b2, x1);

    pack_kernel<<<pgrid, 256, 0, stream>>>(x1, 32, xph, xpl, sqw);
    knn_mfma<<<kgrid, 256, 0, stream>>>(xph, xpl, sqw, nidx);
    edge_mfma<32, 32, 32, float><<<egrid, 256, 0, stream>>>(x1, nidx, E12, E22, c2b1, c2b2, x2);

    pack_kernel<<<pgrid, 256, 0, stream>>>(x2, 32, xph, xpl, sqw);
    knn_mfma<<<kgrid, 256, 0, stream>>>(xph, xpl, sqw, nidx);
    edge_mfma<32, 64, 64, __hip_bfloat16><<<egrid, 256, 0, stream>>>(x2, nidx, E13, E23, c3b1, c3b2, x3);

    mlp_kernel<<<dim3(NROWS / 64), 256, 0, stream>>>(x1, x2, x3, WT1, WT2, WT3, bp,
                                                     mW4, mb4, (float*)d_out);
}